// Round 1
// baseline (200.406 us; speedup 1.0000x reference)
//
#include <hip/hip_runtime.h>
#include <math.h>

// MultiHeadAttention_3728031613617 — bf16-MFMA pipeline v9.
// v9 = v8 + latency attack on all three kernels (everything was <35% util):
//  - flash: T14 register prefetch of next K/V tile (issue loads after the
//    ds_writes of the current tile; L2 latency hides under QK^T/softmax/PV).
//    Swizzle offsets proven j-invariant and hoisted. Main-loop math verbatim.
//  - proj: was 1 wave/SIMD (256 blk x 256 thr, 1 blk/CU). Now 512 threads
//    (2 waves/SIMD) with waves mapped to (row-tile, n-half), same LDS
//    layouts, plus cross-iteration register prefetch of X and W tiles.
//  - prep: LDS-transpose tiles; coalesced reads AND writes, conflict-free
//    (65-stride) banks. Was stride-64-float scatter per lane.

typedef __bf16 bf16;
typedef __bf16 bf16x4v __attribute__((ext_vector_type(4)));
typedef __bf16 bf16x8v __attribute__((ext_vector_type(8)));
typedef float f32x4 __attribute__((ext_vector_type(4)));

namespace {
constexpr int kS = 2048;
constexpr int kD = 512;
constexpr int kRows = 16384;  // 8 * 2048
}

#define MFMA16(a, b, c) __builtin_amdgcn_mfma_f32_16x16x32_bf16((a), (b), (c), 0, 0, 0)

// ---------------------------------------------------------------------------
// Kernel 0: prep. wtg[mat][n=64][k=512] = (bf16)W[mat][k][n]
//           drt[o=512][j=64] = (bf16) sum_h dense[h*64+j, o]
// grid 32 x 256: blocks 0..23 transpose one 64k x 64n tile of w;
// blocks 24..31 each reduce+transpose a 64-wide o-chunk of dense.
// ---------------------------------------------------------------------------
__global__ __launch_bounds__(256) void prep_kernel(const float* __restrict__ w,
                                                   const float* __restrict__ dense,
                                                   bf16* __restrict__ wtg,
                                                   bf16* __restrict__ drt) {
  const int bid = blockIdx.x, tid = threadIdx.x;
  __shared__ float T[64][65];  // padded: bank (r*65+c)%32 == (r+c)%32

  if (bid < 24) {
    const int mat = bid >> 3, k0 = (bid & 7) * 64;
    // read: lane -> n (coalesced 256B); LDS write: lane -> consecutive banks
#pragma unroll
    for (int p = 0; p < 16; ++p) {
      int e = tid + p * 256;       // 0..4095
      int r = e >> 6, n = e & 63;  // k-row, n
      T[r][n] = w[mat * 32768 + (k0 + r) * 64 + n];
    }
    __syncthreads();
    // write: lane -> c (consecutive k, coalesced); T[c][n] stride-65 = no conflict
#pragma unroll
    for (int p = 0; p < 16; ++p) {
      int e = tid + p * 256;
      int n = e >> 6, c = e & 63;
      wtg[(size_t)mat * 32768 + (size_t)n * 512 + k0 + c] = (bf16)T[c][n];
    }
  } else {
    const int o0 = (bid - 24) * 64;
    const int oo = tid & 63, jg = tid >> 6;  // o-offset (lane), j-group of 16
    float a[16];
#pragma unroll
    for (int i = 0; i < 16; ++i) a[i] = 0.f;
#pragma unroll
    for (int h = 0; h < 8; ++h)
#pragma unroll
      for (int i = 0; i < 16; ++i)  // lane -> oo: coalesced 256B rows
        a[i] += dense[(size_t)(h * 64 + jg * 16 + i) * kD + o0 + oo];
#pragma unroll
    for (int i = 0; i < 16; ++i) T[oo][jg * 16 + i] = a[i];  // stride-65: clean
    __syncthreads();
#pragma unroll
    for (int p = 0; p < 16; ++p) {
      int e = tid + p * 256;
      int r = e >> 6, j = e & 63;  // r = o-offset; lane -> j: coalesced write
      drt[(size_t)(o0 + r) * 64 + j] = (bf16)T[r][j];
    }
  }
}

// ---------------------------------------------------------------------------
// Kernel 1: fused QKV projection (x read ONCE). grid 256, block 512 (v9).
// 8 waves: rt = w&3 (row-tile of 16), nh = w>>2 (n-tile half: 6 of 12 tiles).
// Register prefetch of next X/W chunk overlaps MFMA of current chunk.
// ---------------------------------------------------------------------------
__global__ __launch_bounds__(512) void proj_kernel(const float* __restrict__ x,
                                                   const bf16* __restrict__ wtg,
                                                   bf16* __restrict__ wq,
                                                   bf16* __restrict__ wk,
                                                   bf16* __restrict__ wvt) {
  const int bt = blockIdx.x;
  const int tid = threadIdx.x;
  const int w = tid >> 6, tx = tid & 15, quad = (tid >> 4) & 3;
  const int rt = w & 3, nh = w >> 2;
  const int row0 = bt * 64;

  __shared__ bf16 Xs[64 * 72];
  __shared__ bf16 Wts[3 * 64 * 72];

  f32x4 acc[6];
#pragma unroll
  for (int j = 0; j < 6; ++j) acc[j] = (f32x4){0.f, 0.f, 0.f, 0.f};

  float4 xf[2];
  uint4 wf[3];
  auto proj_issue = [&](int K0) {
#pragma unroll
    for (int p = 0; p < 2; ++p) {
      int i4 = tid + p * 512;  // 0..1023 = 64 rows x 16 float4
      int r = i4 >> 4, c4 = (i4 & 15) * 4;
      xf[p] = *(const float4*)&x[(size_t)(row0 + r) * kD + K0 + c4];
    }
#pragma unroll
    for (int p = 0; p < 3; ++p) {
      int cc = tid + p * 512;  // 0..1535 = 3 mats x 64 n x 8 chunks
      int mat = cc >> 9, rem = cc & 511;
      int n = rem >> 3, c8 = (rem & 7) * 8;
      wf[p] = *(const uint4*)&wtg[(size_t)mat * 32768 + (size_t)n * 512 + K0 + c8];
    }
  };

  proj_issue(0);
  for (int k0 = 0; k0 < kD; k0 += 64) {
    __syncthreads();  // prior MFMA reads done before LDS overwrite
#pragma unroll
    for (int p = 0; p < 2; ++p) {
      int i4 = tid + p * 512;
      int r = i4 >> 4, c4 = (i4 & 15) * 4;
      float4 f = xf[p];
      bf16x4v h = {(bf16)f.x, (bf16)f.y, (bf16)f.z, (bf16)f.w};
      *(bf16x4v*)&Xs[r * 72 + c4] = h;
    }
#pragma unroll
    for (int p = 0; p < 3; ++p) {
      int cc = tid + p * 512;
      int mat = cc >> 9, rem = cc & 511;
      int n = rem >> 3, c8 = (rem & 7) * 8;
      *(uint4*)&Wts[(mat * 64 + n) * 72 + c8] = wf[p];
    }
    if (k0 + 64 < kD) proj_issue(k0 + 64);  // latency hides under MFMA below
    __syncthreads();
#pragma unroll
    for (int s = 0; s < 2; ++s) {
      bf16x8v a = *(bf16x8v*)&Xs[(rt * 16 + tx) * 72 + s * 32 + quad * 8];
#pragma unroll
      for (int j = 0; j < 6; ++j) {
        int ntg = nh * 6 + j;  // global n-tile 0..11; mat = ntg>>2, nt = ntg&3
        bf16x8v bfr = *(bf16x8v*)&Wts[(ntg * 16 + tx) * 72 + s * 32 + quad * 8];
        acc[j] = MFMA16(a, bfr, acc[j]);
      }
    }
  }

  // wq / wk (mats 0,1)
#pragma unroll
  for (int j = 0; j < 6; ++j) {
    int ntg = nh * 6 + j, mat = ntg >> 2, nt = ntg & 3;
    if (mat < 2) {
      bf16* dst = mat ? wk : wq;
#pragma unroll
      for (int r = 0; r < 4; ++r) {
        int row_g = row0 + rt * 16 + quad * 4 + r;
        dst[(size_t)row_g * 64 + nt * 16 + tx] = (bf16)acc[j][r];
      }
    }
  }
  __syncthreads();
  bf16* Vt = Xs;  // [64 v][72] transpose staging for wvt
#pragma unroll
  for (int j = 0; j < 6; ++j) {
    int ntg = nh * 6 + j, mat = ntg >> 2, nt = ntg & 3;
    if (mat == 2) {
#pragma unroll
      for (int r = 0; r < 4; ++r)
        Vt[(nt * 16 + tx) * 72 + rt * 16 + quad * 4 + r] = (bf16)acc[j][r];
    }
  }
  __syncthreads();
  {
    int v = tid >> 3, seg = tid & 7;
    *(uint4*)&wvt[(size_t)v * kRows + row0 + seg * 8] =
        *(uint4*)&Vt[v * 72 + seg * 8];
  }
}

// ---------------------------------------------------------------------------
// Kernel 2: flash attention v9 — v8 + register prefetch of next K/V tile.
// grid 512: b = bid&7, qb = bid>>3 (32 Q-rows). Block 512 = 8 waves; wave w
// owns key tiles (t*8+w)*32, t<8. Barrier-free main loop, wave-private 8KB
// slots (P aliases K), XOR swizzle. Tail: combine -> vob bf16 -> dense MFMA
// vs drt -> LDS-staged 32x256 f32 chunks -> full-row float4 stores to out.
// LDS: 64KB slots (reused as OutS) + 1KB Lsh + 4KB vob = 70656 B -> 2 blk/CU.
// ---------------------------------------------------------------------------
__global__ __launch_bounds__(512, 4) void flash_kernel(
    const bf16* __restrict__ wq, const bf16* __restrict__ wk,
    const bf16* __restrict__ wvt, const bf16* __restrict__ drt,
    float* __restrict__ out) {
  const int bid = blockIdx.x;
  const int b = bid & 7, qb = bid >> 3;
  const int q0 = qb * 32;
  const int tid = threadIdx.x;
  const int w = tid >> 6, lane = tid & 63, tx = tid & 15, quad = (tid >> 4) & 3;

  __shared__ __align__(16) char lds[65536];   // 8 waves x 8KB slots
  __shared__ float Lsh[256];                  // 8 waves x 32 rows
  __shared__ __align__(16) bf16 vob[32 * 64]; // combined O, swizzled rows
  bf16* Ksw = (bf16*)(lds + w * 8192);        // 32 keys x 64 c (swizzled)
  bf16* Psw = Ksw;                            // 32 q x 32 k, aliases K[0:16]
  bf16* Vtw = (bf16*)(lds + w * 8192 + 4096); // 64 v x 32 keys (swizzled)

  const bf16* wqb = wq + (size_t)(b * kS) * 64;
  const bf16* wkb = wk + (size_t)(b * kS) * 64;
  const bf16* wvb = wvt + b * kS;

  const int kc0 = (quad ^ (tx & 7)) * 8;        // 64-wide rows, s=0 chunk
  const int kc1 = ((4 + quad) ^ (tx & 7)) * 8;  // s=1 chunk
  const int h2 = (tx ^ (tx >> 2)) & 3;          // 32-wide rows keyed by tx

  // Q fragments: loop-invariant, direct from global (one-time cost)
  bf16x8v aq[2][2];
#pragma unroll
  for (int rt = 0; rt < 2; ++rt)
#pragma unroll
    for (int s = 0; s < 2; ++s)
      aq[rt][s] = *(const bf16x8v*)&wqb[(size_t)(q0 + rt * 16 + tx) * 64 +
                                        s * 32 + quad * 8];

  f32x4 oacc[2][4];
#pragma unroll
  for (int rt = 0; rt < 2; ++rt)
#pragma unroll
    for (int nt = 0; nt < 4; ++nt) oacc[rt][nt] = (f32x4){0.f, 0.f, 0.f, 0.f};
  float lsum[2][4] = {};

  const int ksr = lane >> 3, kslc = lane & 7;  // K staging: 8 lanes/row
  const int vsv = lane >> 2, vsck = lane & 3;  // V staging: 4 lanes/v-row
  // LDS swizzle offsets are tile-invariant: (ksr+8j)&7 == ksr,
  // ((v^(v>>2))&3) with v = vsv+16j == (vsv^(vsv>>2))&3.
  const int koff = (kslc ^ ksr) * 8;
  const int voff = (vsck ^ ((vsv ^ (vsv >> 2)) & 3)) * 8;

  uint4 kreg[4], vreg[4];
  auto kv_issue = [&](int t) {
    const int k0 = (t * 8 + w) * 32;
#pragma unroll
    for (int j = 0; j < 4; ++j) {
      kreg[j] = *(const uint4*)&wkb[(size_t)(k0 + ksr + j * 8) * 64 + kslc * 8];
      vreg[j] = *(const uint4*)&wvb[(size_t)(vsv + j * 16) * kRows + k0 + vsck * 8];
    }
  };

  kv_issue(0);
  for (int t = 0; t < 8; ++t) {
    // drain staged tile into wave-private LDS slot (waits on last issue)
#pragma unroll
    for (int j = 0; j < 4; ++j) {
      *(uint4*)&Ksw[(ksr + j * 8) * 64 + koff] = kreg[j];
      *(uint4*)&Vtw[(vsv + j * 16) * 32 + voff] = vreg[j];
    }
    // prefetch next tile now; L2 latency hides under this tile's compute.
    // (t=7 wraps to tile 0: harmless, keeps the loop body branchless.)
    kv_issue((t + 1) & 7);

    // QK^T + no-max softmax numerator + swizzled P store (C -> A layout)
#pragma unroll
    for (int nt = 0; nt < 2; ++nt) {
      int krow = nt * 16 + tx;
      bf16x8v b0 = *(bf16x8v*)&Ksw[krow * 64 + kc0];
      bf16x8v b1 = *(bf16x8v*)&Ksw[krow * 64 + kc1];
#pragma unroll
      for (int rt = 0; rt < 2; ++rt) {
        f32x4 z = (f32x4){0.f, 0.f, 0.f, 0.f};
        z = MFMA16(aq[rt][0], b0, z);
        z = MFMA16(aq[rt][1], b1, z);
#pragma unroll
        for (int r = 0; r < 4; ++r) {
          float p = __expf(z[r] * 0.1f);
          lsum[rt][r] += p;
          int q = rt * 16 + quad * 4 + r;
          int chunk = nt * 2 + (tx >> 3);
          Psw[q * 32 + ((chunk ^ (r ^ quad)) * 8) + (tx & 7)] = (bf16)p;
        }
      }
    }

    // PV: O[32 q][64 v] += P[32][32] * V[32][64]
#pragma unroll
    for (int rt = 0; rt < 2; ++rt) {
      bf16x8v pa = *(bf16x8v*)&Psw[(rt * 16 + tx) * 32 + ((quad ^ h2) * 8)];
#pragma unroll
      for (int nt = 0; nt < 4; ++nt) {
        bf16x8v vb = *(bf16x8v*)&Vtw[(nt * 16 + tx) * 32 + ((quad ^ h2) * 8)];
        oacc[rt][nt] = MFMA16(pa, vb, oacc[rt][nt]);
      }
    }
  }

  // ---- cross-wave combine (private 8KB f32 regions, no atomics) ----
  __syncthreads();
  float* myO = (float*)(lds + w * 8192);  // 32 x 64 f32 (exactly 8KB)
  float* myL = Lsh + w * 32;
#pragma unroll
  for (int rt = 0; rt < 2; ++rt)
#pragma unroll
    for (int nt = 0; nt < 4; ++nt)
#pragma unroll
      for (int r = 0; r < 4; ++r)
        myO[(rt * 16 + quad * 4 + r) * 64 + nt * 16 + tx] = oacc[rt][nt][r];
#pragma unroll
  for (int rt = 0; rt < 2; ++rt)
#pragma unroll
    for (int r = 0; r < 4; ++r) {
      float v = lsum[rt][r];
#pragma unroll
      for (int m = 1; m < 16; m <<= 1) v += __shfl_xor(v, m, 64);
      if (tx == 0) myL[rt * 16 + quad * 4 + r] = v;
    }
  __syncthreads();

  // combined, normalized O -> vob (bf16, row-swizzled for A-frag reads)
#pragma unroll
  for (int p = 0; p < 4; ++p) {
    int e = tid + p * 512;  // 2048: 32 rows x 64 cols
    int row = e >> 6, col = e & 63;
    float s = 0.f, lt = 0.f;
#pragma unroll
    for (int wv = 0; wv < 8; ++wv) {
      s += ((const float*)(lds + wv * 8192))[e];
      lt += Lsh[wv * 32 + row];
    }
    vob[row * 64 + (((col >> 3) ^ (row & 7)) * 8) + (col & 7)] = (bf16)(s / lt);
  }
  __syncthreads();

  // ---- fused dense epilogue: out[32 x 512] = vob[32 x 64] @ drt^T ----
  bf16x8v av[2][2];
#pragma unroll
  for (int rt = 0; rt < 2; ++rt) {
    av[rt][0] = *(bf16x8v*)&vob[(rt * 16 + tx) * 64 + kc0];
    av[rt][1] = *(bf16x8v*)&vob[(rt * 16 + tx) * 64 + kc1];
  }

  float* OutS = (float*)lds;  // 32 x 260 f32 = 33280 B (aliases dead slots)
#pragma unroll
  for (int c = 0; c < 2; ++c) {  // two 256-col chunks
    if (c) __syncthreads();      // prior chunk's LDS reads done
#pragma unroll
    for (int i = 0; i < 2; ++i) {
      const int ct = c * 16 + w * 2 + i;  // global 16-col tile
      bf16x8v bd0 =
          *(const bf16x8v*)&drt[(size_t)(ct * 16 + tx) * 64 + quad * 8];
      bf16x8v bd1 =
          *(const bf16x8v*)&drt[(size_t)(ct * 16 + tx) * 64 + 32 + quad * 8];
#pragma unroll
      for (int rt = 0; rt < 2; ++rt) {
        f32x4 z = (f32x4){0.f, 0.f, 0.f, 0.f};
        z = MFMA16(av[rt][0], bd0, z);
        z = MFMA16(av[rt][1], bd1, z);
#pragma unroll
        for (int r = 0; r < 4; ++r)
          OutS[(rt * 16 + quad * 4 + r) * 260 + (w * 2 + i) * 16 + tx] = z[r];
      }
    }
    __syncthreads();
    // coalesced full-row stores: 32 rows x 256 f32 = 1KB contiguous per row
#pragma unroll
    for (int p = 0; p < 4; ++p) {
      int e = tid + p * 512;  // 2048 float4
      int row = e >> 6, seg = e & 63;
      *(float4*)&out[(size_t)(b * kS + q0 + row) * kD + c * 256 + seg * 4] =
          *(float4*)&OutS[row * 260 + seg * 4];
    }
  }
}

extern "C" void kernel_launch(void* const* d_in, const int* in_sizes, int n_in,
                              void* d_out, int out_size, void* d_ws,
                              size_t ws_size, hipStream_t stream) {
  const float* x = (const float*)d_in[0];      // [8,2048,512]
  const float* w = (const float*)d_in[1];      // [3,512,64]
  const float* dense = (const float*)d_in[2];  // [512,512]
  float* out = (float*)d_out;                  // [8,2048,512] fp32

  bf16* wq = (bf16*)d_ws;                // 1,048,576 bf16
  bf16* wk = wq + (size_t)kRows * 64;    // 1,048,576
  bf16* wvt = wk + (size_t)kRows * 64;   // 1,048,576  [64][16384]
  bf16* wtg = wvt + (size_t)kRows * 64;  // 98,304     [3][64][512]
  bf16* drt = wtg + 98304;               // 32,768     [512][64]

  prep_kernel<<<32, 256, 0, stream>>>(w, dense, wtg, drt);
  proj_kernel<<<256, 512, 0, stream>>>(x, wtg, wq, wk, wvt);
  flash_kernel<<<512, 512, 0, stream>>>(wq, wk, wvt, drt, out);
}

// Round 2
// 157.584 us; speedup vs baseline: 1.2717x; 1.2717x over previous
//
#include <hip/hip_runtime.h>
#include <math.h>

// MultiHeadAttention_3728031613617 — bf16-MFMA pipeline v10.
// v10 = v9's intent, implemented without the scratch spill.
// v9 post-mortem: lambda-by-reference capture of uint4/float4 ARRAYS forced
// them to scratch (VGPR stayed 64; WRITE_SIZE 39->331MB = spill round-trip).
// v10 uses NAMED SCALAR register variables via macros — nothing addressable.
//  - flash: v8 main-loop math verbatim + named-reg prefetch of next K/V tile.
//  - proj: 512 threads (2 waves/SIMD) + named-reg prefetch, hoisted bases.
//  - prep: coalesced LDS-transpose version (from v9, correct + tiny).

typedef __bf16 bf16;
typedef __bf16 bf16x4v __attribute__((ext_vector_type(4)));
typedef __bf16 bf16x8v __attribute__((ext_vector_type(8)));
typedef float f32x4 __attribute__((ext_vector_type(4)));

namespace {
constexpr int kS = 2048;
constexpr int kD = 512;
constexpr int kRows = 16384;  // 8 * 2048
}

#define MFMA16(a, b, c) __builtin_amdgcn_mfma_f32_16x16x32_bf16((a), (b), (c), 0, 0, 0)

// ---------------------------------------------------------------------------
// Kernel 0: prep. wtg[mat][n=64][k=512] = (bf16)W[mat][k][n]
//           drt[o=512][j=64] = (bf16) sum_h dense[h*64+j, o]
// ---------------------------------------------------------------------------
__global__ __launch_bounds__(256) void prep_kernel(const float* __restrict__ w,
                                                   const float* __restrict__ dense,
                                                   bf16* __restrict__ wtg,
                                                   bf16* __restrict__ drt) {
  const int bid = blockIdx.x, tid = threadIdx.x;
  __shared__ float T[64][65];  // padded: bank (r*65+c)%32 == (r+c)%32

  if (bid < 24) {
    const int mat = bid >> 3, k0 = (bid & 7) * 64;
#pragma unroll
    for (int p = 0; p < 16; ++p) {
      int e = tid + p * 256;       // 0..4095
      int r = e >> 6, n = e & 63;  // k-row, n
      T[r][n] = w[mat * 32768 + (k0 + r) * 64 + n];
    }
    __syncthreads();
#pragma unroll
    for (int p = 0; p < 16; ++p) {
      int e = tid + p * 256;
      int n = e >> 6, c = e & 63;
      wtg[(size_t)mat * 32768 + (size_t)n * 512 + k0 + c] = (bf16)T[c][n];
    }
  } else {
    const int o0 = (bid - 24) * 64;
    const int oo = tid & 63, jg = tid >> 6;
    float a[16];
#pragma unroll
    for (int i = 0; i < 16; ++i) a[i] = 0.f;
#pragma unroll
    for (int h = 0; h < 8; ++h)
#pragma unroll
      for (int i = 0; i < 16; ++i)
        a[i] += dense[(size_t)(h * 64 + jg * 16 + i) * kD + o0 + oo];
#pragma unroll
    for (int i = 0; i < 16; ++i) T[oo][jg * 16 + i] = a[i];
    __syncthreads();
#pragma unroll
    for (int p = 0; p < 16; ++p) {
      int e = tid + p * 256;
      int r = e >> 6, j = e & 63;
      drt[(size_t)(o0 + r) * 64 + j] = (bf16)T[r][j];
    }
  }
}

// ---------------------------------------------------------------------------
// Kernel 1: fused QKV projection. grid 256, block 512 (2 waves/SIMD).
// 8 waves: rt = w&3 (row-tile of 16), nh = w>>2 (6 of 12 n-tiles each).
// Named-register prefetch of next X/W chunk overlaps MFMA of current chunk.
// ---------------------------------------------------------------------------
__global__ __launch_bounds__(512) void proj_kernel(const float* __restrict__ x,
                                                   const bf16* __restrict__ wtg,
                                                   bf16* __restrict__ wq,
                                                   bf16* __restrict__ wk,
                                                   bf16* __restrict__ wvt) {
  const int bt = blockIdx.x;
  const int tid = threadIdx.x;
  const int w = tid >> 6, tx = tid & 15, quad = (tid >> 4) & 3;
  const int rt = w & 3, nh = w >> 2;
  const int row0 = bt * 64;

  __shared__ bf16 Xs[64 * 72];
  __shared__ bf16 Wts[3 * 64 * 72];

  f32x4 acc[6];
#pragma unroll
  for (int j = 0; j < 6; ++j) acc[j] = (f32x4){0.f, 0.f, 0.f, 0.f};

  // k0-invariant staging geometry (p in {0,1} only changes the x row by +32;
  // wtg mat == p exactly since tid<512).
  const int xr0 = tid >> 4, xc4 = (tid & 15) * 4;
  const float* xb0 = &x[(size_t)(row0 + xr0) * kD + xc4];
  const float* xb1 = &x[(size_t)(row0 + xr0 + 32) * kD + xc4];
  const int wn = tid >> 3, wc8 = (tid & 7) * 8;
  const bf16* wb = &wtg[(size_t)wn * 512 + wc8];

  float4 xf0, xf1;
  uint4 wf0, wf1, wf2;
#define PROJ_ISSUE(K0)                        \
  do {                                        \
    xf0 = *(const float4*)(xb0 + (K0));       \
    xf1 = *(const float4*)(xb1 + (K0));       \
    wf0 = *(const uint4*)(wb + (K0));         \
    wf1 = *(const uint4*)(wb + 32768 + (K0)); \
    wf2 = *(const uint4*)(wb + 65536 + (K0)); \
  } while (0)

  PROJ_ISSUE(0);
  for (int k0 = 0; k0 < kD; k0 += 64) {
    __syncthreads();  // prior MFMA reads done before LDS overwrite
    {
      bf16x4v h0 = {(bf16)xf0.x, (bf16)xf0.y, (bf16)xf0.z, (bf16)xf0.w};
      *(bf16x4v*)&Xs[xr0 * 72 + xc4] = h0;
      bf16x4v h1 = {(bf16)xf1.x, (bf16)xf1.y, (bf16)xf1.z, (bf16)xf1.w};
      *(bf16x4v*)&Xs[(xr0 + 32) * 72 + xc4] = h1;
      *(uint4*)&Wts[(0 * 64 + wn) * 72 + wc8] = wf0;
      *(uint4*)&Wts[(1 * 64 + wn) * 72 + wc8] = wf1;
      *(uint4*)&Wts[(2 * 64 + wn) * 72 + wc8] = wf2;
    }
    if (k0 + 64 < kD) PROJ_ISSUE(k0 + 64);  // latency hides under MFMA below
    __syncthreads();
#pragma unroll
    for (int s = 0; s < 2; ++s) {
      bf16x8v a = *(bf16x8v*)&Xs[(rt * 16 + tx) * 72 + s * 32 + quad * 8];
#pragma unroll
      for (int j = 0; j < 6; ++j) {
        int ntg = nh * 6 + j;  // global n-tile 0..11; mat = ntg>>2, nt = ntg&3
        bf16x8v bfr = *(bf16x8v*)&Wts[(ntg * 16 + tx) * 72 + s * 32 + quad * 8];
        acc[j] = MFMA16(a, bfr, acc[j]);
      }
    }
  }

  // wq / wk (mats 0,1)
#pragma unroll
  for (int j = 0; j < 6; ++j) {
    int ntg = nh * 6 + j, mat = ntg >> 2, nt = ntg & 3;
    if (mat < 2) {
      bf16* dst = mat ? wk : wq;
#pragma unroll
      for (int r = 0; r < 4; ++r) {
        int row_g = row0 + rt * 16 + quad * 4 + r;
        dst[(size_t)row_g * 64 + nt * 16 + tx] = (bf16)acc[j][r];
      }
    }
  }
  __syncthreads();
  bf16* Vt = Xs;  // [64 v][72] transpose staging for wvt
#pragma unroll
  for (int j = 0; j < 6; ++j) {
    int ntg = nh * 6 + j, mat = ntg >> 2, nt = ntg & 3;
    if (mat == 2) {
#pragma unroll
      for (int r = 0; r < 4; ++r)
        Vt[(nt * 16 + tx) * 72 + rt * 16 + quad * 4 + r] = (bf16)acc[j][r];
    }
  }
  __syncthreads();
  {
    int v = tid >> 3, seg = tid & 7;
    *(uint4*)&wvt[(size_t)v * kRows + row0 + seg * 8] =
        *(uint4*)&Vt[v * 72 + seg * 8];
  }
}

// ---------------------------------------------------------------------------
// Kernel 2: flash attention v10 — v8 main loop + named-reg K/V prefetch.
// grid 512: b = bid&7, qb = bid>>3 (32 Q-rows). Block 512 = 8 waves; wave w
// owns key tiles (t*8+w)*32, t<8. Barrier-free main loop, wave-private 8KB
// slots (P aliases K), XOR swizzle. Tail: combine -> vob bf16 -> dense MFMA
// vs drt -> LDS-staged 32x256 f32 chunks -> full-row float4 stores to out.
// LDS: 64KB slots (reused as OutS) + 1KB Lsh + 4KB vob = 70656 B -> 2 blk/CU.
// ---------------------------------------------------------------------------
__global__ __launch_bounds__(512, 4) void flash_kernel(
    const bf16* __restrict__ wq, const bf16* __restrict__ wk,
    const bf16* __restrict__ wvt, const bf16* __restrict__ drt,
    float* __restrict__ out) {
  const int bid = blockIdx.x;
  const int b = bid & 7, qb = bid >> 3;
  const int q0 = qb * 32;
  const int tid = threadIdx.x;
  const int w = tid >> 6, lane = tid & 63, tx = tid & 15, quad = (tid >> 4) & 3;

  __shared__ __align__(16) char lds[65536];   // 8 waves x 8KB slots
  __shared__ float Lsh[256];                  // 8 waves x 32 rows
  __shared__ __align__(16) bf16 vob[32 * 64]; // combined O, swizzled rows
  bf16* Ksw = (bf16*)(lds + w * 8192);        // 32 keys x 64 c (swizzled)
  bf16* Psw = Ksw;                            // 32 q x 32 k, aliases K[0:16]
  bf16* Vtw = (bf16*)(lds + w * 8192 + 4096); // 64 v x 32 keys (swizzled)

  const bf16* wqb = wq + (size_t)(b * kS) * 64;
  const bf16* wkb = wk + (size_t)(b * kS) * 64;
  const bf16* wvb = wvt + b * kS;

  const int kc0 = (quad ^ (tx & 7)) * 8;        // 64-wide rows, s=0 chunk
  const int kc1 = ((4 + quad) ^ (tx & 7)) * 8;  // s=1 chunk
  const int h2 = (tx ^ (tx >> 2)) & 3;          // 32-wide rows keyed by tx

  // Q fragments: loop-invariant, direct from global (one-time cost)
  bf16x8v aq[2][2];
#pragma unroll
  for (int rt = 0; rt < 2; ++rt)
#pragma unroll
    for (int s = 0; s < 2; ++s)
      aq[rt][s] = *(const bf16x8v*)&wqb[(size_t)(q0 + rt * 16 + tx) * 64 +
                                        s * 32 + quad * 8];

  f32x4 oacc[2][4];
#pragma unroll
  for (int rt = 0; rt < 2; ++rt)
#pragma unroll
    for (int nt = 0; nt < 4; ++nt) oacc[rt][nt] = (f32x4){0.f, 0.f, 0.f, 0.f};
  float lsum[2][4] = {};

  const int ksr = lane >> 3, kslc = lane & 7;  // K staging: 8 lanes/row
  const int vsv = lane >> 2, vsck = lane & 3;  // V staging: 4 lanes/v-row
  // Swizzle offsets are tile/j-invariant (verified in v9's passing run):
  // (ksr+8j)&7 == ksr;  ((v^(v>>2))&3) with v = vsv+16j == (vsv^(vsv>>2))&3.
  const int koff = (kslc ^ ksr) * 8;
  const int voff = (vsck ^ ((vsv ^ (vsv >> 2)) & 3)) * 8;

  // Per-lane global bases (tile-invariant part hoisted).
  const bf16* kap = &wkb[(size_t)ksr * 64 + kslc * 8];
  const bf16* vap = &wvb[(size_t)vsv * kRows + vsck * 8];

  // NAMED scalar prefetch registers — no arrays, no lambdas (v9 spilled).
  uint4 kr0, kr1, kr2, kr3, vr0, vr1, vr2, vr3;
#define KV_ISSUE(TT)                                          \
  do {                                                        \
    const size_t kb = (size_t)(((TT)*8 + w) * 32);            \
    kr0 = *(const uint4*)(kap + kb * 64);                     \
    kr1 = *(const uint4*)(kap + kb * 64 + 8 * 64);            \
    kr2 = *(const uint4*)(kap + kb * 64 + 16 * 64);           \
    kr3 = *(const uint4*)(kap + kb * 64 + 24 * 64);           \
    vr0 = *(const uint4*)(vap + kb);                          \
    vr1 = *(const uint4*)(vap + kb + (size_t)16 * kRows);     \
    vr2 = *(const uint4*)(vap + kb + (size_t)32 * kRows);     \
    vr3 = *(const uint4*)(vap + kb + (size_t)48 * kRows);     \
  } while (0)

  KV_ISSUE(0);
  for (int t = 0; t < 8; ++t) {
    // drain staged tile into wave-private LDS slot
    *(uint4*)&Ksw[(ksr + 0) * 64 + koff] = kr0;
    *(uint4*)&Ksw[(ksr + 8) * 64 + koff] = kr1;
    *(uint4*)&Ksw[(ksr + 16) * 64 + koff] = kr2;
    *(uint4*)&Ksw[(ksr + 24) * 64 + koff] = kr3;
    *(uint4*)&Vtw[(vsv + 0) * 32 + voff] = vr0;
    *(uint4*)&Vtw[(vsv + 16) * 32 + voff] = vr1;
    *(uint4*)&Vtw[(vsv + 32) * 32 + voff] = vr2;
    *(uint4*)&Vtw[(vsv + 48) * 32 + voff] = vr3;
    // prefetch next tile; L2 latency hides under this tile's compute.
    if (t < 7) KV_ISSUE(t + 1);

    // QK^T + no-max softmax numerator + swizzled P store (C -> A layout)
#pragma unroll
    for (int nt = 0; nt < 2; ++nt) {
      int krow = nt * 16 + tx;
      bf16x8v b0 = *(bf16x8v*)&Ksw[krow * 64 + kc0];
      bf16x8v b1 = *(bf16x8v*)&Ksw[krow * 64 + kc1];
#pragma unroll
      for (int rt = 0; rt < 2; ++rt) {
        f32x4 z = (f32x4){0.f, 0.f, 0.f, 0.f};
        z = MFMA16(aq[rt][0], b0, z);
        z = MFMA16(aq[rt][1], b1, z);
#pragma unroll
        for (int r = 0; r < 4; ++r) {
          float p = __expf(z[r] * 0.1f);
          lsum[rt][r] += p;
          int q = rt * 16 + quad * 4 + r;
          int chunk = nt * 2 + (tx >> 3);
          Psw[q * 32 + ((chunk ^ (r ^ quad)) * 8) + (tx & 7)] = (bf16)p;
        }
      }
    }

    // PV: O[32 q][64 v] += P[32][32] * V[32][64]
#pragma unroll
    for (int rt = 0; rt < 2; ++rt) {
      bf16x8v pa = *(bf16x8v*)&Psw[(rt * 16 + tx) * 32 + ((quad ^ h2) * 8)];
#pragma unroll
      for (int nt = 0; nt < 4; ++nt) {
        bf16x8v vb = *(bf16x8v*)&Vtw[(nt * 16 + tx) * 32 + ((quad ^ h2) * 8)];
        oacc[rt][nt] = MFMA16(pa, vb, oacc[rt][nt]);
      }
    }
  }

  // ---- cross-wave combine (private 8KB f32 regions, no atomics) ----
  __syncthreads();
  float* myO = (float*)(lds + w * 8192);  // 32 x 64 f32 (exactly 8KB)
  float* myL = Lsh + w * 32;
#pragma unroll
  for (int rt = 0; rt < 2; ++rt)
#pragma unroll
    for (int nt = 0; nt < 4; ++nt)
#pragma unroll
      for (int r = 0; r < 4; ++r)
        myO[(rt * 16 + quad * 4 + r) * 64 + nt * 16 + tx] = oacc[rt][nt][r];
#pragma unroll
  for (int rt = 0; rt < 2; ++rt)
#pragma unroll
    for (int r = 0; r < 4; ++r) {
      float v = lsum[rt][r];
#pragma unroll
      for (int m = 1; m < 16; m <<= 1) v += __shfl_xor(v, m, 64);
      if (tx == 0) myL[rt * 16 + quad * 4 + r] = v;
    }
  __syncthreads();

  // combined, normalized O -> vob (bf16, row-swizzled for A-frag reads)
#pragma unroll
  for (int p = 0; p < 4; ++p) {
    int e = tid + p * 512;  // 2048: 32 rows x 64 cols
    int row = e >> 6, col = e & 63;
    float s = 0.f, lt = 0.f;
#pragma unroll
    for (int wv = 0; wv < 8; ++wv) {
      s += ((const float*)(lds + wv * 8192))[e];
      lt += Lsh[wv * 32 + row];
    }
    vob[row * 64 + (((col >> 3) ^ (row & 7)) * 8) + (col & 7)] = (bf16)(s / lt);
  }
  __syncthreads();

  // ---- fused dense epilogue: out[32 x 512] = vob[32 x 64] @ drt^T ----
  bf16x8v av[2][2];
#pragma unroll
  for (int rt = 0; rt < 2; ++rt) {
    av[rt][0] = *(bf16x8v*)&vob[(rt * 16 + tx) * 64 + kc0];
    av[rt][1] = *(bf16x8v*)&vob[(rt * 16 + tx) * 64 + kc1];
  }

  float* OutS = (float*)lds;  // 32 x 260 f32 = 33280 B (aliases dead slots)
#pragma unroll
  for (int c = 0; c < 2; ++c) {  // two 256-col chunks
    if (c) __syncthreads();      // prior chunk's LDS reads done
#pragma unroll
    for (int i = 0; i < 2; ++i) {
      const int ct = c * 16 + w * 2 + i;  // global 16-col tile
      bf16x8v bd0 =
          *(const bf16x8v*)&drt[(size_t)(ct * 16 + tx) * 64 + quad * 8];
      bf16x8v bd1 =
          *(const bf16x8v*)&drt[(size_t)(ct * 16 + tx) * 64 + 32 + quad * 8];
#pragma unroll
      for (int rt = 0; rt < 2; ++rt) {
        f32x4 z = (f32x4){0.f, 0.f, 0.f, 0.f};
        z = MFMA16(av[rt][0], bd0, z);
        z = MFMA16(av[rt][1], bd1, z);
#pragma unroll
        for (int r = 0; r < 4; ++r)
          OutS[(rt * 16 + quad * 4 + r) * 260 + (w * 2 + i) * 16 + tx] = z[r];
      }
    }
    __syncthreads();
    // coalesced full-row stores: 32 rows x 256 f32 = 1KB contiguous per row
#pragma unroll
    for (int p = 0; p < 4; ++p) {
      int e = tid + p * 512;  // 2048 float4
      int row = e >> 6, seg = e & 63;
      *(float4*)&out[(size_t)(b * kS + q0 + row) * kD + c * 256 + seg * 4] =
          *(float4*)&OutS[row * 260 + seg * 4];
    }
  }
}

extern "C" void kernel_launch(void* const* d_in, const int* in_sizes, int n_in,
                              void* d_out, int out_size, void* d_ws,
                              size_t ws_size, hipStream_t stream) {
  const float* x = (const float*)d_in[0];      // [8,2048,512]
  const float* w = (const float*)d_in[1];      // [3,512,64]
  const float* dense = (const float*)d_in[2];  // [512,512]
  float* out = (float*)d_out;                  // [8,2048,512] fp32

  bf16* wq = (bf16*)d_ws;                // 1,048,576 bf16
  bf16* wk = wq + (size_t)kRows * 64;    // 1,048,576
  bf16* wvt = wk + (size_t)kRows * 64;   // 1,048,576  [64][16384]
  bf16* wtg = wvt + (size_t)kRows * 64;  // 98,304     [3][64][512]
  bf16* drt = wtg + 98304;               // 32,768     [512][64]

  prep_kernel<<<32, 256, 0, stream>>>(w, dense, wtg, drt);
  proj_kernel<<<256, 512, 0, stream>>>(x, wtg, wq, wk, wvt);
  flash_kernel<<<512, 512, 0, stream>>>(wq, wk, wvt, drt, out);
}

// Round 3
// 126.961 us; speedup vs baseline: 1.5785x; 1.2412x over previous
//
#include <hip/hip_runtime.h>
#include <math.h>

// MultiHeadAttention_3728031613617 — bf16-MFMA pipeline v11.
// v11 = v10 with ONE change: flash's __launch_bounds__(512,4) -> (512,2).
// v10 post-mortem: VGPR_Count stayed 64 and WRITE_SIZE was still +107MB.
// (512,4) resolves to an 8-waves/EU occupancy floor -> 64-VGPR cap, so the
// named-register K/V prefetch (needs ~32 extra VGPRs) was spilled to scratch
// at the cap. Occupancy is LDS-bound at 2 blocks/CU (70656B) regardless, so
// relaxing to (512,2) raises the VGPR cap to >=128 without losing occupancy.
// Everything else (prep/proj/flash math, swizzles, prefetch) is v10 verbatim.

typedef __bf16 bf16;
typedef __bf16 bf16x4v __attribute__((ext_vector_type(4)));
typedef __bf16 bf16x8v __attribute__((ext_vector_type(8)));
typedef float f32x4 __attribute__((ext_vector_type(4)));

namespace {
constexpr int kS = 2048;
constexpr int kD = 512;
constexpr int kRows = 16384;  // 8 * 2048
}

#define MFMA16(a, b, c) __builtin_amdgcn_mfma_f32_16x16x32_bf16((a), (b), (c), 0, 0, 0)

// ---------------------------------------------------------------------------
// Kernel 0: prep. wtg[mat][n=64][k=512] = (bf16)W[mat][k][n]
//           drt[o=512][j=64] = (bf16) sum_h dense[h*64+j, o]
// ---------------------------------------------------------------------------
__global__ __launch_bounds__(256) void prep_kernel(const float* __restrict__ w,
                                                   const float* __restrict__ dense,
                                                   bf16* __restrict__ wtg,
                                                   bf16* __restrict__ drt) {
  const int bid = blockIdx.x, tid = threadIdx.x;
  __shared__ float T[64][65];  // padded: bank (r*65+c)%32 == (r+c)%32

  if (bid < 24) {
    const int mat = bid >> 3, k0 = (bid & 7) * 64;
#pragma unroll
    for (int p = 0; p < 16; ++p) {
      int e = tid + p * 256;       // 0..4095
      int r = e >> 6, n = e & 63;  // k-row, n
      T[r][n] = w[mat * 32768 + (k0 + r) * 64 + n];
    }
    __syncthreads();
#pragma unroll
    for (int p = 0; p < 16; ++p) {
      int e = tid + p * 256;
      int n = e >> 6, c = e & 63;
      wtg[(size_t)mat * 32768 + (size_t)n * 512 + k0 + c] = (bf16)T[c][n];
    }
  } else {
    const int o0 = (bid - 24) * 64;
    const int oo = tid & 63, jg = tid >> 6;
    float a[16];
#pragma unroll
    for (int i = 0; i < 16; ++i) a[i] = 0.f;
#pragma unroll
    for (int h = 0; h < 8; ++h)
#pragma unroll
      for (int i = 0; i < 16; ++i)
        a[i] += dense[(size_t)(h * 64 + jg * 16 + i) * kD + o0 + oo];
#pragma unroll
    for (int i = 0; i < 16; ++i) T[oo][jg * 16 + i] = a[i];
    __syncthreads();
#pragma unroll
    for (int p = 0; p < 16; ++p) {
      int e = tid + p * 256;
      int r = e >> 6, j = e & 63;
      drt[(size_t)(o0 + r) * 64 + j] = (bf16)T[r][j];
    }
  }
}

// ---------------------------------------------------------------------------
// Kernel 1: fused QKV projection. grid 256, block 512 (2 waves/SIMD).
// 8 waves: rt = w&3 (row-tile of 16), nh = w>>2 (6 of 12 n-tiles each).
// Named-register prefetch of next X/W chunk overlaps MFMA of current chunk.
// ---------------------------------------------------------------------------
__global__ __launch_bounds__(512) void proj_kernel(const float* __restrict__ x,
                                                   const bf16* __restrict__ wtg,
                                                   bf16* __restrict__ wq,
                                                   bf16* __restrict__ wk,
                                                   bf16* __restrict__ wvt) {
  const int bt = blockIdx.x;
  const int tid = threadIdx.x;
  const int w = tid >> 6, tx = tid & 15, quad = (tid >> 4) & 3;
  const int rt = w & 3, nh = w >> 2;
  const int row0 = bt * 64;

  __shared__ bf16 Xs[64 * 72];
  __shared__ bf16 Wts[3 * 64 * 72];

  f32x4 acc[6];
#pragma unroll
  for (int j = 0; j < 6; ++j) acc[j] = (f32x4){0.f, 0.f, 0.f, 0.f};

  // k0-invariant staging geometry (p in {0,1} only changes the x row by +32;
  // wtg mat == p exactly since tid<512).
  const int xr0 = tid >> 4, xc4 = (tid & 15) * 4;
  const float* xb0 = &x[(size_t)(row0 + xr0) * kD + xc4];
  const float* xb1 = &x[(size_t)(row0 + xr0 + 32) * kD + xc4];
  const int wn = tid >> 3, wc8 = (tid & 7) * 8;
  const bf16* wb = &wtg[(size_t)wn * 512 + wc8];

  float4 xf0, xf1;
  uint4 wf0, wf1, wf2;
#define PROJ_ISSUE(K0)                        \
  do {                                        \
    xf0 = *(const float4*)(xb0 + (K0));       \
    xf1 = *(const float4*)(xb1 + (K0));       \
    wf0 = *(const uint4*)(wb + (K0));         \
    wf1 = *(const uint4*)(wb + 32768 + (K0)); \
    wf2 = *(const uint4*)(wb + 65536 + (K0)); \
  } while (0)

  PROJ_ISSUE(0);
  for (int k0 = 0; k0 < kD; k0 += 64) {
    __syncthreads();  // prior MFMA reads done before LDS overwrite
    {
      bf16x4v h0 = {(bf16)xf0.x, (bf16)xf0.y, (bf16)xf0.z, (bf16)xf0.w};
      *(bf16x4v*)&Xs[xr0 * 72 + xc4] = h0;
      bf16x4v h1 = {(bf16)xf1.x, (bf16)xf1.y, (bf16)xf1.z, (bf16)xf1.w};
      *(bf16x4v*)&Xs[(xr0 + 32) * 72 + xc4] = h1;
      *(uint4*)&Wts[(0 * 64 + wn) * 72 + wc8] = wf0;
      *(uint4*)&Wts[(1 * 64 + wn) * 72 + wc8] = wf1;
      *(uint4*)&Wts[(2 * 64 + wn) * 72 + wc8] = wf2;
    }
    if (k0 + 64 < kD) PROJ_ISSUE(k0 + 64);  // latency hides under MFMA below
    __syncthreads();
#pragma unroll
    for (int s = 0; s < 2; ++s) {
      bf16x8v a = *(bf16x8v*)&Xs[(rt * 16 + tx) * 72 + s * 32 + quad * 8];
#pragma unroll
      for (int j = 0; j < 6; ++j) {
        int ntg = nh * 6 + j;  // global n-tile 0..11; mat = ntg>>2, nt = ntg&3
        bf16x8v bfr = *(bf16x8v*)&Wts[(ntg * 16 + tx) * 72 + s * 32 + quad * 8];
        acc[j] = MFMA16(a, bfr, acc[j]);
      }
    }
  }

  // wq / wk (mats 0,1)
#pragma unroll
  for (int j = 0; j < 6; ++j) {
    int ntg = nh * 6 + j, mat = ntg >> 2, nt = ntg & 3;
    if (mat < 2) {
      bf16* dst = mat ? wk : wq;
#pragma unroll
      for (int r = 0; r < 4; ++r) {
        int row_g = row0 + rt * 16 + quad * 4 + r;
        dst[(size_t)row_g * 64 + nt * 16 + tx] = (bf16)acc[j][r];
      }
    }
  }
  __syncthreads();
  bf16* Vt = Xs;  // [64 v][72] transpose staging for wvt
#pragma unroll
  for (int j = 0; j < 6; ++j) {
    int ntg = nh * 6 + j, mat = ntg >> 2, nt = ntg & 3;
    if (mat == 2) {
#pragma unroll
      for (int r = 0; r < 4; ++r)
        Vt[(nt * 16 + tx) * 72 + rt * 16 + quad * 4 + r] = (bf16)acc[j][r];
    }
  }
  __syncthreads();
  {
    int v = tid >> 3, seg = tid & 7;
    *(uint4*)&wvt[(size_t)v * kRows + row0 + seg * 8] =
        *(uint4*)&Vt[v * 72 + seg * 8];
  }
}

// ---------------------------------------------------------------------------
// Kernel 2: flash attention v11 — v8 main loop + named-reg K/V prefetch.
// grid 512: b = bid&7, qb = bid>>3 (32 Q-rows). Block 512 = 8 waves; wave w
// owns key tiles (t*8+w)*32, t<8. Barrier-free main loop, wave-private 8KB
// slots (P aliases K), XOR swizzle. Tail: combine -> vob bf16 -> dense MFMA
// vs drt -> LDS-staged 32x256 f32 chunks -> full-row float4 stores to out.
// LDS: 64KB slots (reused as OutS) + 1KB Lsh + 4KB vob = 70656 B -> 2 blk/CU.
// __launch_bounds__(512,2): occupancy is LDS-bound at 2 blk/CU; (512,4)
// imposed a 64-VGPR cap that spilled the prefetch registers (v9/v10).
// ---------------------------------------------------------------------------
__global__ __launch_bounds__(512, 2) void flash_kernel(
    const bf16* __restrict__ wq, const bf16* __restrict__ wk,
    const bf16* __restrict__ wvt, const bf16* __restrict__ drt,
    float* __restrict__ out) {
  const int bid = blockIdx.x;
  const int b = bid & 7, qb = bid >> 3;
  const int q0 = qb * 32;
  const int tid = threadIdx.x;
  const int w = tid >> 6, lane = tid & 63, tx = tid & 15, quad = (tid >> 4) & 3;

  __shared__ __align__(16) char lds[65536];   // 8 waves x 8KB slots
  __shared__ float Lsh[256];                  // 8 waves x 32 rows
  __shared__ __align__(16) bf16 vob[32 * 64]; // combined O, swizzled rows
  bf16* Ksw = (bf16*)(lds + w * 8192);        // 32 keys x 64 c (swizzled)
  bf16* Psw = Ksw;                            // 32 q x 32 k, aliases K[0:16]
  bf16* Vtw = (bf16*)(lds + w * 8192 + 4096); // 64 v x 32 keys (swizzled)

  const bf16* wqb = wq + (size_t)(b * kS) * 64;
  const bf16* wkb = wk + (size_t)(b * kS) * 64;
  const bf16* wvb = wvt + b * kS;

  const int kc0 = (quad ^ (tx & 7)) * 8;        // 64-wide rows, s=0 chunk
  const int kc1 = ((4 + quad) ^ (tx & 7)) * 8;  // s=1 chunk
  const int h2 = (tx ^ (tx >> 2)) & 3;          // 32-wide rows keyed by tx

  // Q fragments: loop-invariant, direct from global (one-time cost)
  bf16x8v aq[2][2];
#pragma unroll
  for (int rt = 0; rt < 2; ++rt)
#pragma unroll
    for (int s = 0; s < 2; ++s)
      aq[rt][s] = *(const bf16x8v*)&wqb[(size_t)(q0 + rt * 16 + tx) * 64 +
                                        s * 32 + quad * 8];

  f32x4 oacc[2][4];
#pragma unroll
  for (int rt = 0; rt < 2; ++rt)
#pragma unroll
    for (int nt = 0; nt < 4; ++nt) oacc[rt][nt] = (f32x4){0.f, 0.f, 0.f, 0.f};
  float lsum[2][4] = {};

  const int ksr = lane >> 3, kslc = lane & 7;  // K staging: 8 lanes/row
  const int vsv = lane >> 2, vsck = lane & 3;  // V staging: 4 lanes/v-row
  // Swizzle offsets are tile/j-invariant:
  // (ksr+8j)&7 == ksr;  ((v^(v>>2))&3) with v = vsv+16j == (vsv^(vsv>>2))&3.
  const int koff = (kslc ^ ksr) * 8;
  const int voff = (vsck ^ ((vsv ^ (vsv >> 2)) & 3)) * 8;

  // Per-lane global bases (tile-invariant part hoisted).
  const bf16* kap = &wkb[(size_t)ksr * 64 + kslc * 8];
  const bf16* vap = &wvb[(size_t)vsv * kRows + vsck * 8];

  // NAMED scalar prefetch registers — no arrays, no lambdas.
  uint4 kr0, kr1, kr2, kr3, vr0, vr1, vr2, vr3;
#define KV_ISSUE(TT)                                          \
  do {                                                        \
    const size_t kb = (size_t)(((TT)*8 + w) * 32);            \
    kr0 = *(const uint4*)(kap + kb * 64);                     \
    kr1 = *(const uint4*)(kap + kb * 64 + 8 * 64);            \
    kr2 = *(const uint4*)(kap + kb * 64 + 16 * 64);           \
    kr3 = *(const uint4*)(kap + kb * 64 + 24 * 64);           \
    vr0 = *(const uint4*)(vap + kb);                          \
    vr1 = *(const uint4*)(vap + kb + (size_t)16 * kRows);     \
    vr2 = *(const uint4*)(vap + kb + (size_t)32 * kRows);     \
    vr3 = *(const uint4*)(vap + kb + (size_t)48 * kRows);     \
  } while (0)

  KV_ISSUE(0);
  for (int t = 0; t < 8; ++t) {
    // drain staged tile into wave-private LDS slot
    *(uint4*)&Ksw[(ksr + 0) * 64 + koff] = kr0;
    *(uint4*)&Ksw[(ksr + 8) * 64 + koff] = kr1;
    *(uint4*)&Ksw[(ksr + 16) * 64 + koff] = kr2;
    *(uint4*)&Ksw[(ksr + 24) * 64 + koff] = kr3;
    *(uint4*)&Vtw[(vsv + 0) * 32 + voff] = vr0;
    *(uint4*)&Vtw[(vsv + 16) * 32 + voff] = vr1;
    *(uint4*)&Vtw[(vsv + 32) * 32 + voff] = vr2;
    *(uint4*)&Vtw[(vsv + 48) * 32 + voff] = vr3;
    // prefetch next tile; L2 latency hides under this tile's compute.
    if (t < 7) KV_ISSUE(t + 1);

    // QK^T + no-max softmax numerator + swizzled P store (C -> A layout)
#pragma unroll
    for (int nt = 0; nt < 2; ++nt) {
      int krow = nt * 16 + tx;
      bf16x8v b0 = *(bf16x8v*)&Ksw[krow * 64 + kc0];
      bf16x8v b1 = *(bf16x8v*)&Ksw[krow * 64 + kc1];
#pragma unroll
      for (int rt = 0; rt < 2; ++rt) {
        f32x4 z = (f32x4){0.f, 0.f, 0.f, 0.f};
        z = MFMA16(aq[rt][0], b0, z);
        z = MFMA16(aq[rt][1], b1, z);
#pragma unroll
        for (int r = 0; r < 4; ++r) {
          float p = __expf(z[r] * 0.1f);
          lsum[rt][r] += p;
          int q = rt * 16 + quad * 4 + r;
          int chunk = nt * 2 + (tx >> 3);
          Psw[q * 32 + ((chunk ^ (r ^ quad)) * 8) + (tx & 7)] = (bf16)p;
        }
      }
    }

    // PV: O[32 q][64 v] += P[32][32] * V[32][64]
#pragma unroll
    for (int rt = 0; rt < 2; ++rt) {
      bf16x8v pa = *(bf16x8v*)&Psw[(rt * 16 + tx) * 32 + ((quad ^ h2) * 8)];
#pragma unroll
      for (int nt = 0; nt < 4; ++nt) {
        bf16x8v vb = *(bf16x8v*)&Vtw[(nt * 16 + tx) * 32 + ((quad ^ h2) * 8)];
        oacc[rt][nt] = MFMA16(pa, vb, oacc[rt][nt]);
      }
    }
  }

  // ---- cross-wave combine (private 8KB f32 regions, no atomics) ----
  __syncthreads();
  float* myO = (float*)(lds + w * 8192);  // 32 x 64 f32 (exactly 8KB)
  float* myL = Lsh + w * 32;
#pragma unroll
  for (int rt = 0; rt < 2; ++rt)
#pragma unroll
    for (int nt = 0; nt < 4; ++nt)
#pragma unroll
      for (int r = 0; r < 4; ++r)
        myO[(rt * 16 + quad * 4 + r) * 64 + nt * 16 + tx] = oacc[rt][nt][r];
#pragma unroll
  for (int rt = 0; rt < 2; ++rt)
#pragma unroll
    for (int r = 0; r < 4; ++r) {
      float v = lsum[rt][r];
#pragma unroll
      for (int m = 1; m < 16; m <<= 1) v += __shfl_xor(v, m, 64);
      if (tx == 0) myL[rt * 16 + quad * 4 + r] = v;
    }
  __syncthreads();

  // combined, normalized O -> vob (bf16, row-swizzled for A-frag reads)
#pragma unroll
  for (int p = 0; p < 4; ++p) {
    int e = tid + p * 512;  // 2048: 32 rows x 64 cols
    int row = e >> 6, col = e & 63;
    float s = 0.f, lt = 0.f;
#pragma unroll
    for (int wv = 0; wv < 8; ++wv) {
      s += ((const float*)(lds + wv * 8192))[e];
      lt += Lsh[wv * 32 + row];
    }
    vob[row * 64 + (((col >> 3) ^ (row & 7)) * 8) + (col & 7)] = (bf16)(s / lt);
  }
  __syncthreads();

  // ---- fused dense epilogue: out[32 x 512] = vob[32 x 64] @ drt^T ----
  bf16x8v av[2][2];
#pragma unroll
  for (int rt = 0; rt < 2; ++rt) {
    av[rt][0] = *(bf16x8v*)&vob[(rt * 16 + tx) * 64 + kc0];
    av[rt][1] = *(bf16x8v*)&vob[(rt * 16 + tx) * 64 + kc1];
  }

  float* OutS = (float*)lds;  // 32 x 260 f32 = 33280 B (aliases dead slots)
#pragma unroll
  for (int c = 0; c < 2; ++c) {  // two 256-col chunks
    if (c) __syncthreads();      // prior chunk's LDS reads done
#pragma unroll
    for (int i = 0; i < 2; ++i) {
      const int ct = c * 16 + w * 2 + i;  // global 16-col tile
      bf16x8v bd0 =
          *(const bf16x8v*)&drt[(size_t)(ct * 16 + tx) * 64 + quad * 8];
      bf16x8v bd1 =
          *(const bf16x8v*)&drt[(size_t)(ct * 16 + tx) * 64 + 32 + quad * 8];
#pragma unroll
      for (int rt = 0; rt < 2; ++rt) {
        f32x4 z = (f32x4){0.f, 0.f, 0.f, 0.f};
        z = MFMA16(av[rt][0], bd0, z);
        z = MFMA16(av[rt][1], bd1, z);
#pragma unroll
        for (int r = 0; r < 4; ++r)
          OutS[(rt * 16 + quad * 4 + r) * 260 + (w * 2 + i) * 16 + tx] = z[r];
      }
    }
    __syncthreads();
    // coalesced full-row stores: 32 rows x 256 f32 = 1KB contiguous per row
#pragma unroll
    for (int p = 0; p < 4; ++p) {
      int e = tid + p * 512;  // 2048 float4
      int row = e >> 6, seg = e & 63;
      *(float4*)&out[(size_t)(b * kS + q0 + row) * kD + c * 256 + seg * 4] =
          *(float4*)&OutS[row * 260 + seg * 4];
    }
  }
}

extern "C" void kernel_launch(void* const* d_in, const int* in_sizes, int n_in,
                              void* d_out, int out_size, void* d_ws,
                              size_t ws_size, hipStream_t stream) {
  const float* x = (const float*)d_in[0];      // [8,2048,512]
  const float* w = (const float*)d_in[1];      // [3,512,64]
  const float* dense = (const float*)d_in[2];  // [512,512]
  float* out = (float*)d_out;                  // [8,2048,512] fp32

  bf16* wq = (bf16*)d_ws;                // 1,048,576 bf16
  bf16* wk = wq + (size_t)kRows * 64;    // 1,048,576
  bf16* wvt = wk + (size_t)kRows * 64;   // 1,048,576  [64][16384]
  bf16* wtg = wvt + (size_t)kRows * 64;  // 98,304     [3][64][512]
  bf16* drt = wtg + 98304;               // 32,768     [512][64]

  prep_kernel<<<32, 256, 0, stream>>>(w, dense, wtg, drt);
  proj_kernel<<<256, 512, 0, stream>>>(x, wtg, wq, wk, wvt);
  flash_kernel<<<512, 512, 0, stream>>>(wq, wk, wvt, drt, out);
}